// Round 1
// baseline (32480.066 us; speedup 1.0000x reference)
//
#include <hip/hip_runtime.h>
#include <math.h>

#define BATCH 32768
#define NMAT 32
#define LDA 33
#define MELEM 1024
#define NSWEEP 8
#define MPB 16
#define GB (BATCH / MPB)   // 2048 blocks for batch passes
#define G0 512             // blocks for mean partial pass

// ws layout (float offsets)
#define WS_M0    0
#define WS_MS0   1024
#define WS_MIS0  2048
#define WS_T     3072
#define WS_MIS1  4096
#define WS_P     5120
#define WS_D2    5184                      // GB floats
#define WS_W     8192                      // BATCH*32 floats (primary path)
#define WS_FLOATS_PRIMARY (WS_W + BATCH * NMAT)

__device__ __forceinline__ void load_mat(float* dst, const float* __restrict__ g, int tid) {
    for (int e = tid; e < MELEM; e += 64) dst[(e >> 5) * LDA + (e & 31)] = g[e];
}
__device__ __forceinline__ void store_mat(float* __restrict__ g, const float* src, int tid) {
    for (int e = tid; e < MELEM; e += 64) g[e] = src[(e >> 5) * LDA + (e & 31)];
}

// C = A * B, all [32][LDA] in LDS. Caller handles barriers.
__device__ __forceinline__ void matmul32(float* C, const float* A, const float* Bm, int tid) {
    for (int e = tid; e < MELEM; e += 64) {
        int r = e >> 5, c = e & 31;
        float acc = 0.f;
#pragma unroll
        for (int k = 0; k < 32; ++k) acc += A[r * LDA + k] * Bm[k * LDA + c];
        C[r * LDA + c] = acc;
    }
}

// D = U * diag(fw) * U^T  (columns of U are eigenvectors). Caller barriers.
__device__ __forceinline__ void recon32(float* D, const float* U, const float* fw, int tid) {
    for (int e = tid; e < MELEM; e += 64) {
        int r = e >> 5, c = e & 31;
        float acc = 0.f;
#pragma unroll
        for (int j = 0; j < 32; ++j) acc += U[r * LDA + j] * fw[j] * U[c * LDA + j];
        D[r * LDA + c] = acc;
    }
}

// Parallel cyclic Jacobi on symmetric 32x32 in LDS. Diag(A) -> eigenvalues.
// If WANTV, Vv gets eigenvectors as columns. tid in [0,64).
template <bool WANTV>
__device__ void jacobi32(float* A, float* Vv, int tid,
                         float* csc, float* css, int* prow, int* qrow) {
    if (WANTV) {
        for (int e = tid; e < MELEM; e += 64) {
            int r = e >> 5, c = e & 31;
            Vv[r * LDA + c] = (r == c) ? 1.0f : 0.0f;
        }
    }
    __syncthreads();
    for (int sweep = 0; sweep < NSWEEP; ++sweep) {
        for (int round = 0; round < 31; ++round) {
            if (tid < 16) {
                int k = tid, p, q;
                if (k == 0) { p = 31; q = round; }
                else { p = (round + k) % 31; q = (round - k + 31) % 31; }
                float app = A[p * LDA + p], aqq = A[q * LDA + q], apq = A[p * LDA + q];
                float c = 1.0f, s = 0.0f;
                if (fabsf(apq) > 1e-30f) {
                    float tau = (aqq - app) / (2.0f * apq);
                    float t = copysignf(1.0f / (fabsf(tau) + sqrtf(1.0f + tau * tau)), tau);
                    c = rsqrtf(1.0f + t * t);
                    s = t * c;
                }
                csc[k] = c; css[k] = s; prow[k] = p; qrow[k] = q;
            }
            __syncthreads();
            // column update: A <- A * J
#pragma unroll
            for (int it = 0; it < 8; ++it) {
                int e = tid + 64 * it;
                int k = e >> 5, r = e & 31;
                int p = prow[k], q = qrow[k];
                float c = csc[k], s = css[k];
                float ap = A[r * LDA + p], aq = A[r * LDA + q];
                A[r * LDA + p] = c * ap - s * aq;
                A[r * LDA + q] = s * ap + c * aq;
            }
            __syncthreads();
            // row update: A <- J^T * A ; and V <- V * J
#pragma unroll
            for (int it = 0; it < 8; ++it) {
                int e = tid + 64 * it;
                int k = e >> 5, cc = e & 31;
                int p = prow[k], q = qrow[k];
                float c = csc[k], s = css[k];
                float ap = A[p * LDA + cc], aq = A[q * LDA + cc];
                A[p * LDA + cc] = c * ap - s * aq;
                A[q * LDA + cc] = s * ap + c * aq;
            }
            if (WANTV) {
#pragma unroll
                for (int it = 0; it < 8; ++it) {
                    int e = tid + 64 * it;
                    int k = e >> 5, r = e & 31;
                    int p = prow[k], q = qrow[k];
                    float c = csc[k], s = css[k];
                    float vp = Vv[r * LDA + p], vq = Vv[r * LDA + q];
                    Vv[r * LDA + p] = c * vp - s * vq;
                    Vv[r * LDA + q] = s * vp + c * vq;
                }
            }
            __syncthreads();
        }
    }
}

// ---- Pass A: batch arithmetic mean ----
__global__ __launch_bounds__(256) void k_mean_partial(const float* __restrict__ x,
                                                      float* __restrict__ part) {
    int g = blockIdx.x, tid = threadIdx.x;
    const float* base = x + (size_t)g * 64 * MELEM;
    float a0 = 0, a1 = 0, a2 = 0, a3 = 0;
    for (int b = 0; b < 64; ++b) {
        const float* m = base + b * MELEM;
        a0 += m[tid]; a1 += m[tid + 256]; a2 += m[tid + 512]; a3 += m[tid + 768];
    }
    float* o = part + (size_t)g * MELEM;
    o[tid] = a0; o[tid + 256] = a1; o[tid + 512] = a2; o[tid + 768] = a3;
}

__global__ __launch_bounds__(256) void k_reduce(const float* __restrict__ part,
                                                float* __restrict__ dst, int G, float scale) {
    __shared__ float sm[256];
    int e = blockIdx.x, tid = threadIdx.x;
    float acc = 0.f;
    for (int g = tid; g < G; g += 256) acc += part[(size_t)g * MELEM + e];
    sm[tid] = acc;
    __syncthreads();
    for (int off = 128; off > 0; off >>= 1) {
        if (tid < off) sm[tid] += sm[tid + off];
        __syncthreads();
    }
    if (tid == 0) dst[e] = sm[0] * scale;
}

// ---- prep0: eigh(M0) -> m_s0, m_is0 ----
__global__ __launch_bounds__(64) void k_prep0(float* __restrict__ ws) {
    __shared__ float A[32 * LDA], V[32 * LDA], fw[32], wv[32];
    __shared__ float csc[16], css[16];
    __shared__ int pr[16], qr[16];
    int tid = threadIdx.x;
    load_mat(A, ws + WS_M0, tid);
    __syncthreads();
    jacobi32<true>(A, V, tid, csc, css, pr, qr);
    if (tid < 32) wv[tid] = A[tid * LDA + tid];
    __syncthreads();
    if (tid < 32) fw[tid] = sqrtf(wv[tid]);
    __syncthreads();
    recon32(A, V, fw, tid);
    __syncthreads();
    store_mat(ws + WS_MS0, A, tid);
    if (tid < 32) fw[tid] = rsqrtf(wv[tid]);
    __syncthreads();
    recon32(A, V, fw, tid);
    __syncthreads();
    store_mat(ws + WS_MIS0, A, tid);
}

// ---- pass B: t partials = sum logm(m_is0 x m_is0) ----
__global__ __launch_bounds__(64) void k_pass_logm(const float* __restrict__ x,
                                                  const float* __restrict__ ws,
                                                  float* __restrict__ part) {
    __shared__ float A[32 * LDA], V[32 * LDA], S[32 * LDA], Lacc[32 * LDA], fw[32];
    __shared__ float csc[16], css[16];
    __shared__ int pr[16], qr[16];
    int tid = threadIdx.x;
    load_mat(S, ws + WS_MIS0, tid);
    for (int e = tid; e < MELEM; e += 64) Lacc[(e >> 5) * LDA + (e & 31)] = 0.f;
    __syncthreads();
    for (int m = 0; m < MPB; ++m) {
        size_t i = (size_t)blockIdx.x * MPB + m;
        load_mat(A, x + i * MELEM, tid);
        __syncthreads();
        matmul32(V, S, A, tid);   // V = S*x
        __syncthreads();
        matmul32(A, V, S, tid);   // A = S*x*S
        __syncthreads();
        jacobi32<true>(A, V, tid, csc, css, pr, qr);
        if (tid < 32) fw[tid] = logf(A[tid * LDA + tid]);
        __syncthreads();
        for (int e = tid; e < MELEM; e += 64) {
            int r = e >> 5, c = e & 31;
            float acc = 0.f;
#pragma unroll
            for (int j = 0; j < 32; ++j) acc += V[r * LDA + j] * fw[j] * V[c * LDA + j];
            Lacc[r * LDA + c] += acc;
        }
        __syncthreads();
    }
    store_mat(part + (size_t)blockIdx.x * MELEM, Lacc, tid);
}

// ---- prep1: mean1 = m_s0 expm(t) m_s0 ; m_is1 ----
__global__ __launch_bounds__(64) void k_prep1(float* __restrict__ ws) {
    __shared__ float A[32 * LDA], V[32 * LDA], S[32 * LDA], T[32 * LDA], fw[32];
    __shared__ float csc[16], css[16];
    __shared__ int pr[16], qr[16];
    int tid = threadIdx.x;
    load_mat(A, ws + WS_T, tid);
    __syncthreads();
    jacobi32<true>(A, V, tid, csc, css, pr, qr);
    if (tid < 32) fw[tid] = expf(A[tid * LDA + tid]);
    __syncthreads();
    recon32(T, V, fw, tid);       // T = expm(t)
    load_mat(S, ws + WS_MS0, tid);
    __syncthreads();
    matmul32(A, S, T, tid);       // A = m_s0 * E
    __syncthreads();
    matmul32(V, A, S, tid);       // V = mean1
    __syncthreads();
    jacobi32<true>(V, A, tid, csc, css, pr, qr);  // eig of mean1: vals in V diag, vecs in A
    if (tid < 32) fw[tid] = rsqrtf(V[tid * LDA + tid]);
    __syncthreads();
    recon32(T, A, fw, tid);       // T = m_is1
    __syncthreads();
    store_mat(ws + WS_MIS1, T, tid);
}

// ---- pass C: Z = m_is1 x m_is1; eigh; d2 partials; store V,w (or Z) ----
template <bool STOREV>
__global__ __launch_bounds__(64) void k_pass_dist(const float* __restrict__ x,
                                                  float* __restrict__ ws,
                                                  float* __restrict__ dout) {
    __shared__ float A[32 * LDA], V[32 * LDA], S[32 * LDA];
    __shared__ float csc[16], css[16];
    __shared__ int pr[16], qr[16];
    int tid = threadIdx.x;
    load_mat(S, ws + WS_MIS1, tid);
    __syncthreads();
    float d2acc = 0.f;
    for (int m = 0; m < MPB; ++m) {
        size_t i = (size_t)blockIdx.x * MPB + m;
        load_mat(A, x + i * MELEM, tid);
        __syncthreads();
        matmul32(V, S, A, tid);
        __syncthreads();
        matmul32(A, V, S, tid);   // A = Z
        __syncthreads();
        if (!STOREV) store_mat(dout + i * MELEM, A, tid);  // keep Z for re-eigh
        jacobi32<STOREV>(A, V, tid, csc, css, pr, qr);
        if (STOREV) {
            store_mat(dout + i * MELEM, V, tid);
            if (tid < 32) ws[WS_W + i * 32 + tid] = A[tid * LDA + tid];
        }
        float l2 = 0.f;
        if (tid < 32) {
            float lg = logf(A[tid * LDA + tid]);
            l2 = lg * lg;
        }
#pragma unroll
        for (int off = 16; off > 0; off >>= 1) l2 += __shfl_down(l2, off, 32);
        if (tid == 0) d2acc += l2;
        __syncthreads();
    }
    if (tid == 0) ws[WS_D2 + blockIdx.x] = d2acc;
}

__global__ __launch_bounds__(256) void k_finish_p(float* __restrict__ ws,
                                                  const float* __restrict__ scale) {
    __shared__ float sm[256];
    int tid = threadIdx.x;
    float acc = 0.f;
    for (int g = tid; g < GB; g += 256) acc += ws[WS_D2 + g];
    sm[tid] = acc;
    __syncthreads();
    for (int off = 128; off > 0; off >>= 1) {
        if (tid < off) sm[tid] += sm[tid + off];
        __syncthreads();
    }
    if (tid == 0) {
        float sd = sqrtf(sm[0] / (float)BATCH);
        ws[WS_P] = scale[0] / (sd + 1e-5f);
    }
}

// ---- pass D primary: out = V diag(w^p) V^T from stored V,w ----
__global__ __launch_bounds__(64) void k_out_recon(float* __restrict__ dout,
                                                  const float* __restrict__ ws) {
    __shared__ float V[32 * LDA], fw[32];
    int tid = threadIdx.x;
    float p = ws[WS_P];
    for (int m = 0; m < MPB; ++m) {
        size_t i = (size_t)blockIdx.x * MPB + m;
        load_mat(V, dout + i * MELEM, tid);
        if (tid < 32) fw[tid] = expf(p * logf(ws[WS_W + i * 32 + tid]));
        __syncthreads();
        for (int e = tid; e < MELEM; e += 64) {
            int r = e >> 5, c = e & 31;
            float acc = 0.f;
#pragma unroll
            for (int j = 0; j < 32; ++j) acc += V[r * LDA + j] * fw[j] * V[c * LDA + j];
            dout[i * MELEM + e] = acc;
        }
        __syncthreads();
    }
}

// ---- pass D fallback: re-eigh Z stored in dout ----
__global__ __launch_bounds__(64) void k_out_eigh(float* __restrict__ dout,
                                                 const float* __restrict__ ws) {
    __shared__ float A[32 * LDA], V[32 * LDA], fw[32];
    __shared__ float csc[16], css[16];
    __shared__ int pr[16], qr[16];
    int tid = threadIdx.x;
    float p = ws[WS_P];
    for (int m = 0; m < MPB; ++m) {
        size_t i = (size_t)blockIdx.x * MPB + m;
        load_mat(A, dout + i * MELEM, tid);
        __syncthreads();
        jacobi32<true>(A, V, tid, csc, css, pr, qr);
        if (tid < 32) fw[tid] = expf(p * logf(A[tid * LDA + tid]));
        __syncthreads();
        for (int e = tid; e < MELEM; e += 64) {
            int r = e >> 5, c = e & 31;
            float acc = 0.f;
#pragma unroll
            for (int j = 0; j < 32; ++j) acc += V[r * LDA + j] * fw[j] * V[c * LDA + j];
            dout[i * MELEM + e] = acc;
        }
        __syncthreads();
    }
}

extern "C" void kernel_launch(void* const* d_in, const int* in_sizes, int n_in,
                              void* d_out, int out_size, void* d_ws, size_t ws_size,
                              hipStream_t stream) {
    const float* x = (const float*)d_in[0];
    const float* scale = (const float*)d_in[1];
    float* out = (float*)d_out;
    float* ws = (float*)d_ws;
    bool primary = ws_size >= (size_t)WS_FLOATS_PRIMARY * sizeof(float);

    // batch mean -> M0 (partials staged in d_out, free until final pass)
    k_mean_partial<<<G0, 256, 0, stream>>>(x, out);
    k_reduce<<<MELEM, 256, 0, stream>>>(out, ws + WS_M0, G0, 1.0f / (float)BATCH);
    k_prep0<<<1, 64, 0, stream>>>(ws);
    // Karcher tangent mean
    k_pass_logm<<<GB, 64, 0, stream>>>(x, ws, out);
    k_reduce<<<MELEM, 256, 0, stream>>>(out, ws + WS_T, GB, 1.0f / (float)BATCH);
    k_prep1<<<1, 64, 0, stream>>>(ws);
    // distance pass (+ store eigh results)
    if (primary)
        k_pass_dist<true><<<GB, 64, 0, stream>>>(x, ws, out);
    else
        k_pass_dist<false><<<GB, 64, 0, stream>>>(x, ws, out);
    k_finish_p<<<1, 256, 0, stream>>>(ws, scale);
    // output
    if (primary)
        k_out_recon<<<GB, 64, 0, stream>>>(out, ws);
    else
        k_out_eigh<<<GB, 64, 0, stream>>>(out, ws);
}

// Round 2
// 3570.480 us; speedup vs baseline: 9.0968x; 9.0968x over previous
//
#include <hip/hip_runtime.h>
#include <math.h>

#define BATCH 32768
#define MELEM 1024
#define NSWEEP_BATCH 7
#define NSWEEP_PREP 8
#define MPW 4                    // matrix-PAIRS per wave
#define NW (BATCH / (2 * MPW))   // 4096 waves in batch passes
#define NBLK (NW / 4)            // 1024 blocks (4 waves/block)
#define G0 512                   // blocks for mean partial pass
#define EPSF 1e-5f

// ws layout (float offsets)
#define WS_M0    0
#define WS_MS0   1024
#define WS_MIS0  2048
#define WS_T     3072
#define WS_MIS1  4096
#define WS_P     5120
#define WS_D2    5184            // NW floats

// per-wave LDS stage: union of X[2][1024] and Gt[2][32][36] = 2304 floats, + wt[2][32]
#define STG_F 2368
#define GT_H 1152                // 32*36
#define GT_LD 36

// ---------------- register helpers ----------------

__device__ __forceinline__ float colnorm(const float (&col)[32]) {
    float a0 = 0, a1 = 0, a2 = 0, a3 = 0;
#pragma unroll
    for (int k = 0; k < 32; k += 4) {
        a0 = fmaf(col[k], col[k], a0);
        a1 = fmaf(col[k + 1], col[k + 1], a1);
        a2 = fmaf(col[k + 2], col[k + 2], a2);
        a3 = fmaf(col[k + 3], col[k + 3], a3);
    }
    return (a0 + a1) + (a2 + a3);
}

// One-sided (Hestenes) Jacobi. Lane (h,c) owns column c of its matrix.
// XOR pair ordering: round m pairs column c with c^m. All register indices static.
__device__ __forceinline__ void onesided_sweeps(float (&col)[32], float &nrm, int nsweeps) {
    for (int sw = 0; sw < nsweeps; ++sw) {
        for (int m = 1; m < 32; ++m) {
            float t[32];
            float npart = __shfl_xor(nrm, m);
            float a0 = 0, a1 = 0, a2 = 0, a3 = 0;
#pragma unroll
            for (int k = 0; k < 32; k += 4) {
                t[k] = __shfl_xor(col[k], m);
                t[k + 1] = __shfl_xor(col[k + 1], m);
                t[k + 2] = __shfl_xor(col[k + 2], m);
                t[k + 3] = __shfl_xor(col[k + 3], m);
                a0 = fmaf(col[k], t[k], a0);
                a1 = fmaf(col[k + 1], t[k + 1], a1);
                a2 = fmaf(col[k + 2], t[k + 2], a2);
                a3 = fmaf(col[k + 3], t[k + 3], a3);
            }
            float apq = (a0 + a1) + (a2 + a3);
            // rotate only if meaningfully non-orthogonal (both partners agree)
            if (apq * apq > 1e-14f * nrm * npart) {
                float tau = (npart - nrm) * 0.5f / apq;
                float tt = copysignf(1.f / (fabsf(tau) + sqrtf(fmaf(tau, tau, 1.f))), tau);
                float cc = rsqrtf(fmaf(tt, tt, 1.f));
                float ss = tt * cc;
                nrm = cc * cc * nrm - 2.f * cc * ss * apq + ss * ss * npart;
#pragma unroll
                for (int k = 0; k < 32; ++k) col[k] = fmaf(cc, col[k], -ss * t[k]);
            }
        }
    }
}

// z = (S * X * S) column c.  Xh: this half's matrix, row-major linear [32][32] in LDS.
// Sl: row-major [32][32] in LDS (block-shared). sreg: S column c in registers.
__device__ __forceinline__ void sxs_col(const float* Xh, const float* Sl,
                                        const float (&sreg)[32], float (&z)[32]) {
    float u[32];
#pragma unroll
    for (int i = 0; i < 32; ++i) {
        float a0 = 0, a1 = 0, a2 = 0, a3 = 0;
#pragma unroll
        for (int k = 0; k < 32; k += 4) {
            const float4 xr = *reinterpret_cast<const float4*>(&Xh[i * 32 + k]);
            a0 = fmaf(xr.x, sreg[k], a0);
            a1 = fmaf(xr.y, sreg[k + 1], a1);
            a2 = fmaf(xr.z, sreg[k + 2], a2);
            a3 = fmaf(xr.w, sreg[k + 3], a3);
        }
        u[i] = (a0 + a1) + (a2 + a3);
    }
#pragma unroll
    for (int i = 0; i < 32; ++i) {
        float a0 = 0, a1 = 0, a2 = 0, a3 = 0;
#pragma unroll
        for (int k = 0; k < 32; k += 4) {
            const float4 sr = *reinterpret_cast<const float4*>(&Sl[i * 32 + k]);
            a0 = fmaf(sr.x, u[k], a0);
            a1 = fmaf(sr.y, u[k + 1], a1);
            a2 = fmaf(sr.z, u[k + 2], a2);
            a3 = fmaf(sr.w, u[k + 3], a3);
        }
        z[i] = (a0 + a1) + (a2 + a3);
    }
}

// Stage this lane's column into Gt (row c = column c of G) and its coefficient into wt.
__device__ __forceinline__ void stage_gt(float* Gth, float* wth, int c,
                                         const float (&col)[32], float wtv) {
#pragma unroll
    for (int k = 0; k < 32; k += 4)
        *reinterpret_cast<float4*>(&Gth[c * GT_LD + k]) =
            make_float4(col[k], col[k + 1], col[k + 2], col[k + 3]);
    wth[c] = wtv;
}

// acc[i] += sum_j wt[j] * Gt[j][c] * Gt[j][i]   (= [f(A)]_{i,c})
__device__ __forceinline__ void recon_accum(const float* Gth, const float* wth, int c,
                                            float (&acc)[32]) {
    for (int j = 0; j < 32; ++j) {
        float coef = wth[j] * Gth[j * GT_LD + c];
#pragma unroll
        for (int k = 0; k < 32; k += 4) {
            const float4 g = *reinterpret_cast<const float4*>(&Gth[j * GT_LD + k]);
            acc[k] = fmaf(coef, g.x, acc[k]);
            acc[k + 1] = fmaf(coef, g.y, acc[k + 1]);
            acc[k + 2] = fmaf(coef, g.z, acc[k + 2]);
            acc[k + 3] = fmaf(coef, g.w, acc[k + 3]);
        }
    }
}

__device__ __forceinline__ float half_reduce(float v) {
    v += __shfl_xor(v, 1); v += __shfl_xor(v, 2); v += __shfl_xor(v, 4);
    v += __shfl_xor(v, 8); v += __shfl_xor(v, 16);
    return v;
}

// ---------------- pass A: batch arithmetic mean ----------------

__global__ __launch_bounds__(256) void k_mean_partial(const float* __restrict__ x,
                                                      float* __restrict__ part) {
    int g = blockIdx.x, tid = threadIdx.x;
    const float* base = x + (size_t)g * 64 * MELEM;
    float a0 = 0, a1 = 0, a2 = 0, a3 = 0;
    for (int b = 0; b < 64; ++b) {
        const float* m = base + b * MELEM;
        a0 += m[tid]; a1 += m[tid + 256]; a2 += m[tid + 512]; a3 += m[tid + 768];
    }
    float* o = part + (size_t)g * MELEM;
    o[tid] = a0; o[tid + 256] = a1; o[tid + 512] = a2; o[tid + 768] = a3;
}

__global__ __launch_bounds__(256) void k_reduce(const float* __restrict__ part,
                                                float* __restrict__ dst, int G, float scale) {
    __shared__ float sm[256];
    int e = blockIdx.x, tid = threadIdx.x;
    float acc = 0.f;
    for (int g = tid; g < G; g += 256) acc += part[(size_t)g * MELEM + e];
    sm[tid] = acc;
    __syncthreads();
    for (int off = 128; off > 0; off >>= 1) {
        if (tid < off) sm[tid] += sm[tid + off];
        __syncthreads();
    }
    if (tid == 0) dst[e] = sm[0] * scale;
}

// ---------------- prep0: eigh(M0) -> m_s0 (M0^1/2), m_is0 (M0^-1/2) ----------------

__global__ __launch_bounds__(64) void k_prep0(float* __restrict__ ws) {
    __shared__ alignas(16) float stage[STG_F];
    const int lane = threadIdx.x, h = lane >> 5, c = lane & 31;
    float col[32];
#pragma unroll
    for (int i = 0; i < 32; ++i) col[i] = ws[WS_M0 + i * 32 + c];
    float nrm = colnorm(col);
    onesided_sweeps(col, nrm, NSWEEP_PREP);
    nrm = colnorm(col);
    float* Gth = &stage[h * GT_H];
    float* wth = &stage[2304 + h * 32];
    float lnn = logf(nrm);
    stage_gt(Gth, wth, c, col, expf(-0.75f * lnn));   // lam^0.5 / lam^2
    float acc[32];
#pragma unroll
    for (int i = 0; i < 32; ++i) acc[i] = 0.f;
    recon_accum(Gth, wth, c, acc);
    if (h == 0) {
#pragma unroll
        for (int i = 0; i < 32; ++i) ws[WS_MS0 + i * 32 + c] = acc[i];
    }
    wth[c] = expf(-1.25f * lnn);                      // lam^-0.5 / lam^2
#pragma unroll
    for (int i = 0; i < 32; ++i) acc[i] = 0.f;
    recon_accum(Gth, wth, c, acc);
    if (h == 0) {
#pragma unroll
        for (int i = 0; i < 32; ++i) ws[WS_MIS0 + i * 32 + c] = acc[i];
    }
}

// ---------------- pass B: partials of sum logm(m_is0 x m_is0) ----------------

__global__ __launch_bounds__(256, 3) void k_pass_logm(const float* __restrict__ x,
                                                      const float* __restrict__ ws,
                                                      float* __restrict__ part) {
    __shared__ alignas(16) float Sl[1024];
    __shared__ alignas(16) float stage[4][STG_F];
    const int tid = threadIdx.x;
    const int wid = tid >> 6, lane = tid & 63, h = lane >> 5, c = lane & 31;
    for (int e = tid; e < 1024; e += 256) Sl[e] = ws[WS_MIS0 + e];
    __syncthreads();
    float* Xw = &stage[wid][0];
    const float* Xh = Xw + h * 1024;
    float* Gth = &stage[wid][h * GT_H];
    float* wth = &stage[wid][2304 + h * 32];
    float Lacc[32];
#pragma unroll
    for (int i = 0; i < 32; ++i) Lacc[i] = 0.f;
    const int gw = blockIdx.x * 4 + wid;
    for (int mm = 0; mm < MPW; ++mm) {
        const size_t pairBase = ((size_t)(gw * MPW + mm)) * 2048;
        const float4* gx = reinterpret_cast<const float4*>(x + pairBase);
        float4* X4 = reinterpret_cast<float4*>(Xw);
#pragma unroll
        for (int ch = 0; ch < 8; ++ch) X4[ch * 64 + lane] = gx[ch * 64 + lane];
        float sreg[32];
#pragma unroll
        for (int k = 0; k < 32; ++k) sreg[k] = Sl[k * 32 + c];
        float col[32];
        sxs_col(Xh, Sl, sreg, col);
        float nrm = colnorm(col);
        onesided_sweeps(col, nrm, NSWEEP_BATCH);
        nrm = colnorm(col);
        float wtv = 0.5f * logf(nrm) / nrm;           // log(lam) / lam^2
        stage_gt(Gth, wth, c, col, wtv);
        recon_accum(Gth, wth, c, Lacc);
    }
#pragma unroll
    for (int i = 0; i < 32; ++i) {
        float v = Lacc[i] + __shfl_xor(Lacc[i], 32);
        if (h == 0) part[(size_t)gw * MELEM + i * 32 + c] = v;
    }
}

// ---------------- prep1: mean1 = m_s0 expm(t) m_s0 ; m_is1 = mean1^-1/2 ----------------

__global__ __launch_bounds__(64) void k_prep1(float* __restrict__ ws) {
    __shared__ alignas(16) float Sl[1024];
    __shared__ alignas(16) float stage[STG_F];
    const int lane = threadIdx.x, h = lane >> 5, c = lane & 31;
    float* Xw = &stage[0];
    const float* Xh = Xw + h * 1024;
    float* Gth = &stage[h * GT_H];
    float* wth = &stage[2304 + h * 32];

    // t is symmetric indefinite: shift by alpha*I (alpha > ||t||_F >= |lam_min|)
    float col[32];
#pragma unroll
    for (int i = 0; i < 32; ++i) col[i] = ws[WS_T + i * 32 + c];
    float nrm = colnorm(col);
    float fro2 = half_reduce(nrm);
    float alpha = sqrtf(fro2) + 1.0f;
#pragma unroll
    for (int i = 0; i < 32; ++i) col[i] += (i == c) ? alpha : 0.f;
    nrm = colnorm(col);
    onesided_sweeps(col, nrm, NSWEEP_PREP);
    nrm = colnorm(col);
    float nu = sqrtf(nrm);                             // eig of t+alpha I
    stage_gt(Gth, wth, c, col, expf(nu - alpha) / nrm);
    float acc[32];
#pragma unroll
    for (int i = 0; i < 32; ++i) acc[i] = 0.f;
    recon_accum(Gth, wth, c, acc);                     // acc = expm(t) col c
    // stage E into X layout, load S = m_s0
#pragma unroll
    for (int i = 0; i < 32; ++i) Xw[h * 1024 + i * 32 + c] = acc[i];
    for (int e = lane; e < 1024; e += 64) Sl[e] = ws[WS_MS0 + e];
    __syncthreads();
    float sreg[32];
#pragma unroll
    for (int k = 0; k < 32; ++k) sreg[k] = Sl[k * 32 + c];
    sxs_col(Xh, Sl, sreg, col);                        // mean1 = m_s0 E m_s0
    nrm = colnorm(col);
    onesided_sweeps(col, nrm, NSWEEP_PREP);
    nrm = colnorm(col);
    stage_gt(Gth, wth, c, col, expf(-1.25f * logf(nrm)));
#pragma unroll
    for (int i = 0; i < 32; ++i) acc[i] = 0.f;
    recon_accum(Gth, wth, c, acc);
    if (h == 0) {
#pragma unroll
        for (int i = 0; i < 32; ++i) ws[WS_MIS1 + i * 32 + c] = acc[i];
    }
}

// ---------------- pass C: Z = m_is1 x m_is1; eigh; store G in d_out; d2 partials ----------------

__global__ __launch_bounds__(256, 3) void k_pass_dist(const float* __restrict__ x,
                                                      float* __restrict__ ws,
                                                      float* __restrict__ outG) {
    __shared__ alignas(16) float Sl[1024];
    __shared__ alignas(16) float stage[4][STG_F];
    const int tid = threadIdx.x;
    const int wid = tid >> 6, lane = tid & 63, h = lane >> 5, c = lane & 31;
    for (int e = tid; e < 1024; e += 256) Sl[e] = ws[WS_MIS1 + e];
    __syncthreads();
    float* Xw = &stage[wid][0];
    const float* Xh = Xw + h * 1024;
    const int gw = blockIdx.x * 4 + wid;
    float d2acc = 0.f;
    for (int mm = 0; mm < MPW; ++mm) {
        const size_t pairBase = ((size_t)(gw * MPW + mm)) * 2048;
        const float4* gx = reinterpret_cast<const float4*>(x + pairBase);
        float4* X4 = reinterpret_cast<float4*>(Xw);
#pragma unroll
        for (int ch = 0; ch < 8; ++ch) X4[ch * 64 + lane] = gx[ch * 64 + lane];
        float sreg[32];
#pragma unroll
        for (int k = 0; k < 32; ++k) sreg[k] = Sl[k * 32 + c];
        float col[32];
        sxs_col(Xh, Sl, sreg, col);
        float nrm = colnorm(col);
        onesided_sweeps(col, nrm, NSWEEP_BATCH);
        nrm = colnorm(col);
        // store G columns (coalesced by row)
#pragma unroll
        for (int i = 0; i < 32; ++i) outG[pairBase + h * 1024 + i * 32 + c] = col[i];
        float lg = 0.5f * logf(nrm);
        float l2 = lg * lg;
#pragma unroll
        for (int m = 1; m <= 32; m <<= 1) l2 += __shfl_xor(l2, m);
        d2acc += l2;
    }
    if (lane == 0) ws[WS_D2 + gw] = d2acc;
}

__global__ __launch_bounds__(256) void k_finish_p(float* __restrict__ ws,
                                                  const float* __restrict__ scale) {
    __shared__ float sm[256];
    int tid = threadIdx.x;
    float acc = 0.f;
    for (int g = tid; g < NW; g += 256) acc += ws[WS_D2 + g];
    sm[tid] = acc;
    __syncthreads();
    for (int off = 128; off > 0; off >>= 1) {
        if (tid < off) sm[tid] += sm[tid + off];
        __syncthreads();
    }
    if (tid == 0) {
        float sd = sqrtf(sm[0] / (float)BATCH);
        ws[WS_P] = scale[0] / (sd + EPSF);
    }
}

// ---------------- pass D: out = G diag(nrm^(p/2-1)) G^T from stored G ----------------

__global__ __launch_bounds__(256, 4) void k_out_recon(float* __restrict__ outG,
                                                      const float* __restrict__ ws) {
    __shared__ alignas(16) float stage[4][STG_F];
    const int tid = threadIdx.x;
    const int wid = tid >> 6, lane = tid & 63, h = lane >> 5, c = lane & 31;
    float* Gth = &stage[wid][h * GT_H];
    float* wth = &stage[wid][2304 + h * 32];
    const float p = ws[WS_P];
    const float ex = 0.5f * p - 1.0f;                  // lam^p / lam^2 = nrm^(p/2-1)
    const int gw = blockIdx.x * 4 + wid;
    for (int mm = 0; mm < MPW; ++mm) {
        const size_t pairBase = ((size_t)(gw * MPW + mm)) * 2048;
        float col[32];
#pragma unroll
        for (int i = 0; i < 32; ++i) col[i] = outG[pairBase + h * 1024 + i * 32 + c];
        float nrm = colnorm(col);
        stage_gt(Gth, wth, c, col, expf(ex * logf(nrm)));
        float acc[32];
#pragma unroll
        for (int i = 0; i < 32; ++i) acc[i] = 0.f;
        recon_accum(Gth, wth, c, acc);
#pragma unroll
        for (int i = 0; i < 32; ++i) outG[pairBase + h * 1024 + i * 32 + c] = acc[i];
    }
}

// ---------------- launch ----------------

extern "C" void kernel_launch(void* const* d_in, const int* in_sizes, int n_in,
                              void* d_out, int out_size, void* d_ws, size_t ws_size,
                              hipStream_t stream) {
    const float* x = (const float*)d_in[0];
    const float* scale = (const float*)d_in[1];
    float* out = (float*)d_out;
    float* ws = (float*)d_ws;

    k_mean_partial<<<G0, 256, 0, stream>>>(x, out);
    k_reduce<<<MELEM, 256, 0, stream>>>(out, ws + WS_M0, G0, 1.0f / (float)BATCH);
    k_prep0<<<1, 64, 0, stream>>>(ws);
    k_pass_logm<<<NBLK, 256, 0, stream>>>(x, ws, out);
    k_reduce<<<MELEM, 256, 0, stream>>>(out, ws + WS_T, NW, 1.0f / (float)BATCH);
    k_prep1<<<1, 64, 0, stream>>>(ws);
    k_pass_dist<<<NBLK, 256, 0, stream>>>(x, ws, out);
    k_finish_p<<<1, 256, 0, stream>>>(ws, scale);
    k_out_recon<<<NBLK, 256, 0, stream>>>(out, ws);
}